// Round 3
// baseline (252.725 us; speedup 1.0000x reference)
//
#include <hip/hip_runtime.h>

// VectorQuantizer: inputs [32,256,2048] f32, weight [1024,256] f32
// out0 = quantized [32,256,2048] f32, out1 = argmin indices [65536] (as f32)
//
// Round 9: REGISTER-RESIDENT X (hi), one barrier per step.
// Round 8 was barrier/latency-bound (2 barriers/step, ds_write publish on the
// critical path, MfmaUtil 24% with nothing else busy). Restructure:
//  - Each wave's B-operand hi fragments (32 t x 256 d) = 16 f16x8 = 64 VGPRs,
//    loaded ONCE in the prologue (they are reused by all 8 k-groups).
//  - Xl (lo) stays LDS-persistent at [0,32K): 2 b128 reads/step.
//  - W staging returns to the verified round-6 global_load_lds pattern with a
//    DOUBLE-buffered 2x16KB Wbuf at [32K,64K): one __syncthreads per step
//    (top barrier drains vmcnt -> buf[cur] resident; s+1 loads issued right
//    after, covered by the full compute phase).
//  - Xh prologue scratch occupies [32K,64K) and dies before W(0) is issued.
// LDS = 64 KB -> 2 blocks/CU; VGPR ~210 -> 2 waves/SIMD.
// Chunk loop fully unrolled so all frag-array indices are compile-time.
//
// Numerics (verified rounds 2-8, unchanged): dist = fp32( fp32(xnorm+wnorm)
// - fp32(2dot) ), dot = fp16x2-split 3-product MFMA in chunk-ascending order
// (hi; ah*bl; al*bh), W pre-scaled by 1024 (exact pow2), lo terms scaled 2^24;
// xnorm f64 (oct-partials, shfl-combined); argmin strict '<' ascending k +
// index-min tie-break. W LDS region bytes identical to rounds 6-8.

#define VQ_B   32
#define VQ_D   256
#define VQ_T   2048
#define VQ_K   1024

typedef _Float16 f16x8 __attribute__((ext_vector_type(8)));
typedef _Float16 f16x4 __attribute__((ext_vector_type(4)));
typedef float    f32x4 __attribute__((ext_vector_type(4)));

#define GLOAD_LDS16(gaddr, laddr) \
  __builtin_amdgcn_global_load_lds((const __attribute__((address_space(1))) void*)(gaddr), \
                                   (__attribute__((address_space(3))) void*)(laddr), 16, 0, 0)

// ---------------- kernel 1: W prep only (64 blocks), verified round-5 body.
__global__ __launch_bounds__(256) void vq_wprep_kernel(
    const float* __restrict__ w, float* __restrict__ wnorm,
    _Float16* __restrict__ Wh, _Float16* __restrict__ Wl)
{
    __shared__ double ws_[16][16];
    const int tid = threadIdx.x;
    const int kk  = tid >> 4;
    const int dg  = tid & 15;
    const int k   = blockIdx.x * 16 + kk;
    const float* src = w + (size_t)k * VQ_D + dg * 16;
    double s = 0.0;
    #pragma unroll
    for (int q = 0; q < 4; ++q) {
        float4 v = *(const float4*)(src + q * 4);
        s += (double)v.x * v.x + (double)v.y * v.y
           + (double)v.z * v.z + (double)v.w * v.w;
        const float e4[4] = {v.x, v.y, v.z, v.w};
        f16x4 hv, lv;
        #pragma unroll
        for (int j = 0; j < 4; ++j) {
            const float es = e4[j] * 1024.0f;          // exact pow2 scale
            const _Float16 h = (_Float16)es;
            hv[j] = h;
            lv[j] = (_Float16)((es - (float)h) * 16777216.0f);
        }
        *(f16x4*)(Wh + (size_t)k * VQ_D + dg * 16 + q * 4) = hv;
        *(f16x4*)(Wl + (size_t)k * VQ_D + dg * 16 + q * 4) = lv;
    }
    ws_[kk][dg] = s;
    __syncthreads();
    if (dg == 0) {
        double acc = 0.0;
        #pragma unroll
        for (int g = 0; g < 16; ++g) acc += ws_[kk][g];  // fixed order
        wnorm[k] = (float)acc;
    }
}

// ---------------- kernel 2: reg-resident-X MFMA distance GEMM + argmin + gather
// 1024 blocks (b = blk>>5, t-tile 64), 4 waves: wm = k-half, wn = t-half.
// Wave tile = 64 k x 32 t (frags 4x2).
// LDS: [0,32K) Xl persistent (layout ((c*4+oct)*64 + t)*16B)
//      [32K,64K) prologue: Xh scratch (same layout); main loop: W dbuf
//                2 x 16 regions x 1024 B (regions 0-7 Wh, 8-15 Wl;
//                region byte m16*16+quad*256 = k-row m16, d-octet quad).
__global__ __launch_bounds__(256, 2) void vq_mfma_kernel(
    const _Float16* __restrict__ Wh, const _Float16* __restrict__ Wl,
    const float* __restrict__ inp,
    const float* __restrict__ wnorm,
    const float* __restrict__ w,
    float* __restrict__ outq, float* __restrict__ outi)
{
    __shared__ alignas(16) char lds[65536];
    __shared__ float xns[64];
    char* Xl  = lds;
    char* Xhs = lds + 32768;                  // prologue scratch / W dbuf

    const int tid  = threadIdx.x;
    const int lane = tid & 63;
    const int wv   = tid >> 6;                // wave 0..3
    const int m16  = lane & 15;
    const int quad = lane >> 4;
    const int wm   = wv & 1;                  // k half (0..63 / 64..127)
    const int wn   = wv >> 1;                 // t half (0..31 / 32..63)
    const int b    = blockIdx.x >> 5;
    const int tt0  = (blockIdx.x & 31) * 64;
    const long bt  = (long)b * VQ_T + tt0;

    // ---- prologue: load raw X once, split, stage Xh (scratch) + Xl (LDS),
    // accumulate xnorm in f64 (verified order: d = c*32 + oct*8 + j ascending,
    // oct-partials combined by shfl butterfly).
    const int xt = m16 + wv * 16;
    double xacc = 0.0;
    {
        float xv[2][8];
        const float* xp0 = inp + ((size_t)b * VQ_D + quad * 8) * VQ_T + tt0 + xt;
        #pragma unroll
        for (int j = 0; j < 8; ++j)
            xv[0][j] = xp0[(size_t)j * VQ_T];
        #pragma unroll
        for (int c = 0; c < 8; ++c) {
            if (c < 7) {
                const float* xpn = inp
                    + ((size_t)b * VQ_D + (c + 1) * 32 + quad * 8) * VQ_T
                    + tt0 + xt;
                #pragma unroll
                for (int j = 0; j < 8; ++j)
                    xv[(c + 1) & 1][j] = xpn[(size_t)j * VQ_T];
            }
            f16x8 hv, lv;
            #pragma unroll
            for (int j = 0; j < 8; ++j) {
                const float x = xv[c & 1][j];
                xacc += (double)x * (double)x;             // ascending d
                const _Float16 h = (_Float16)x;
                hv[j] = h;
                lv[j] = (_Float16)((x - (float)h) * 16777216.0f);
            }
            const int off = ((c * 4 + quad) * 64 + xt) * 16;
            *(f16x8*)(Xhs + off) = hv;
            *(f16x8*)(Xl  + off) = lv;
        }
    }
    xacc += __shfl_xor(xacc, 16, 64);
    xacc += __shfl_xor(xacc, 32, 64);
    if (quad == 0) xns[xt] = (float)xacc;
    __syncthreads();                             // X staged + xns visible

    // ---- one-time: wave's B hi fragments -> registers (reused by all 8 kg)
    f16x8 bhr[8][2];
    #pragma unroll
    for (int c = 0; c < 8; ++c)
        #pragma unroll
        for (int f = 0; f < 2; ++f)
            bhr[c][f] = *(const f16x8*)(Xhs +
                ((c * 4 + quad) * 64 + wn * 32 + f * 16 + m16) * 16);
    float xnr[2];
    #pragma unroll
    for (int f = 0; f < 2; ++f)
        xnr[f] = xns[wn * 32 + f * 16 + m16];
    __syncthreads();                             // Xh scratch dead -> W dbuf

    // ---- W staging pointers: wave wv stages regions wv*4..wv*4+3
    // (set = wv>>1 -> Wh/Wl, hf = wv&1, f = i). Source = 64B row-chunks.
    const char* gbase = (const char*)((wv >> 1) ? Wl : Wh);
    const char* gp[4];
    #pragma unroll
    for (int i = 0; i < 4; ++i)
        gp[i] = gbase + (size_t)((wv & 1) * 64 + i * 16 + m16) * 512 + quad * 16;

    // issue W(step 0) into buf 0
    #pragma unroll
    for (int i = 0; i < 4; ++i)
        GLOAD_LDS16(gp[i], Xhs + (wv * 4 + i) * 1024);
    #pragma unroll
    for (int i = 0; i < 4; ++i) gp[i] += 64;     // advance for step-1 issue

    float bestv[2] = {3.0e38f, 3.0e38f};
    int   besti[2] = {0, 0};
    f32x4 acch[4][2], accl[4][2];

    // ---- main loop: 8 k-groups x 8 unrolled d-chunks, ONE barrier per step.
    for (int g = 0; g < 8; ++g) {
        #pragma unroll
        for (int c = 0; c < 8; ++c) {
            char* const Wcur = Xhs + (c & 1) * 16384;
            char* const Wnxt = Xhs + ((c & 1) ^ 1) * 16384;
            __syncthreads();         // drains vmcnt -> Wcur resident;
                                     // orders prior reads of Wnxt
            if (g < 7 || c < 7) {    // issue W(s+1); covered by this compute
                #pragma unroll
                for (int i = 0; i < 4; ++i)
                    GLOAD_LDS16(gp[i], Wnxt + (wv * 4 + i) * 1024);
                const long adv = (c == 6) ? (65536L - 448L) : 64L;
                #pragma unroll
                for (int i = 0; i < 4; ++i) gp[i] += adv;
            }
            if (c == 0) {
                #pragma unroll
                for (int fm = 0; fm < 4; ++fm)
                    #pragma unroll
                    for (int fn = 0; fn < 2; ++fn) {
                        acch[fm][fn] = (f32x4){0.f, 0.f, 0.f, 0.f};
                        accl[fm][fn] = (f32x4){0.f, 0.f, 0.f, 0.f};
                    }
            }

            f16x8 ah[4], al[4], bl[2];
            #pragma unroll
            for (int fm = 0; fm < 4; ++fm) {
                ah[fm] = *(const f16x8*)(Wcur + (wm * 4 + fm) * 1024 + lane * 16);
                al[fm] = *(const f16x8*)(Wcur + (8 + wm * 4 + fm) * 1024 + lane * 16);
            }
            #pragma unroll
            for (int f = 0; f < 2; ++f)
                bl[f] = *(const f16x8*)(Xl +
                    ((c * 4 + quad) * 64 + wn * 32 + f * 16 + m16) * 16);

            #pragma unroll
            for (int fm = 0; fm < 4; ++fm)
                #pragma unroll
                for (int fn = 0; fn < 2; ++fn) {
                    acch[fm][fn] = __builtin_amdgcn_mfma_f32_16x16x32_f16(
                        ah[fm], bhr[c][fn], acch[fm][fn], 0, 0, 0);
                    accl[fm][fn] = __builtin_amdgcn_mfma_f32_16x16x32_f16(
                        ah[fm], bl[fn], accl[fm][fn], 0, 0, 0);
                    accl[fm][fn] = __builtin_amdgcn_mfma_f32_16x16x32_f16(
                        al[fm], bhr[c][fn], accl[fm][fn], 0, 0, 0);
                }

            if (c == 7) {
                const int k0 = g * 128;
                // scores, reference fp32 rounding chain; strict '<' over
                // ascending k => ties resolve to lowest index (np.argmin)
                #pragma unroll
                for (int fm = 0; fm < 4; ++fm) {
                    #pragma unroll
                    for (int r = 0; r < 4; ++r) {
                        const int kg = k0 + wm * 64 + fm * 16 + quad * 4 + r;
                        const float wnk = wnorm[kg];
                        #pragma unroll
                        for (int fn = 0; fn < 2; ++fn) {
                            const float t1 = xnr[fn] + wnk;
                            const float d2 = (acch[fm][fn][r]
                                              + accl[fm][fn][r] * 5.9604644775390625e-8f)
                                             * 0.001953125f;
                            const float sc = t1 - d2;
                            if (sc < bestv[fn]) { bestv[fn] = sc; besti[fn] = kg; }
                        }
                    }
                }
            }
        }
    }

    // cross-lane argmin: lanes {c, c+16, c+32, c+48} share a t-column
    float rv[2]; int ri[2];
    #pragma unroll
    for (int fn = 0; fn < 2; ++fn) {
        float bv = bestv[fn]; int bi = besti[fn];
        #pragma unroll
        for (int mask = 16; mask <= 32; mask <<= 1) {
            const float ov = __shfl_xor(bv, mask, 64);
            const int   oi = __shfl_xor(bi, mask, 64);
            if (ov < bv || (ov == bv && oi < bi)) { bv = ov; bi = oi; }
        }
        rv[fn] = bv; ri[fn] = bi;
    }

    // cross-wave (wm 0 vs 1) reduce via LDS overlay (all loop LDS reads are
    // ordered before these writes by the barrier below)
    __syncthreads();
    float* sv = (float*)lds;                 // [2][64]
    int*   si = (int*)(lds + 1024);          // [2][64]
    if (quad == 0) {
        #pragma unroll
        for (int fn = 0; fn < 2; ++fn) {
            const int tl = wn * 32 + fn * 16 + m16;
            sv[wm * 64 + tl] = rv[fn];
            si[wm * 64 + tl] = ri[fn];
        }
    }
    __syncthreads();
    if (tid < 64) {
        const float v0 = sv[tid], v1 = sv[64 + tid];
        const int   i0 = si[tid], i1 = si[64 + tid];
        const int   bi = (v1 < v0 || (v1 == v0 && i1 < i0)) ? i1 : i0;
        si[tid] = bi;
        outi[bt + tid] = (float)bi;
    }
    __syncthreads();

    // quantized output: outq[b][d][t] = w[best[t]][d]  (verified epilogue)
    {
        const int t  = tid & 63;
        const int dq = tid >> 6;
        const int bi = si[t];
        const float* wrow = w + (size_t)bi * VQ_D + dq * 64;
        float* obase = outq + ((size_t)b * VQ_D + (size_t)dq * 64) * VQ_T + tt0 + t;
        #pragma unroll 4
        for (int dd = 0; dd < 64; dd += 4) {
            float4 v = *(const float4*)(wrow + dd);
            obase[(size_t)(dd + 0) * VQ_T] = v.x;
            obase[(size_t)(dd + 1) * VQ_T] = v.y;
            obase[(size_t)(dd + 2) * VQ_T] = v.z;
            obase[(size_t)(dd + 3) * VQ_T] = v.w;
        }
    }
}

extern "C" void kernel_launch(void* const* d_in, const int* in_sizes, int n_in,
                              void* d_out, int out_size, void* d_ws, size_t ws_size,
                              hipStream_t stream) {
    const float* inp = (const float*)d_in[0];
    const float* w   = (const float*)d_in[1];
    float* outq  = (float*)d_out;
    float* outi  = outq + (size_t)VQ_B * VQ_D * VQ_T;   // indices appended flat

    float*    wnorm = (float*)d_ws;                     // [1024]
    _Float16* Wh    = (_Float16*)(wnorm + VQ_K);        // [1024*256]
    _Float16* Wl    = Wh + (size_t)VQ_K * VQ_D;
    // total ws use: ~1.03 MB

    vq_wprep_kernel<<<dim3(VQ_K / 16), dim3(256), 0, stream>>>(w, wnorm, Wh, Wl);
    vq_mfma_kernel<<<dim3(VQ_B * (VQ_T / 64)), dim3(256), 0, stream>>>(
        Wh, Wl, inp, wnorm, w, outq, outi);
}

// Round 4
// 239.473 us; speedup vs baseline: 1.0553x; 1.0553x over previous
//
#include <hip/hip_runtime.h>

// VectorQuantizer: inputs [32,256,2048] f32, weight [1024,256] f32
// out0 = quantized [32,256,2048] f32, out1 = argmin indices [65536] (as f32)
//
// Round 10: COUNTED-vmcnt 3-buffer W pipeline (T3/T4).
// Round 9 was stall-bound: __syncthreads() per step = s_waitcnt vmcnt(0) drain
// of the W prefetch issued ~1 step earlier, 64x per block, at 8 waves/CU.
// MfmaUtil 23% ~= the fraction of time the MFMA pipe could even be fed.
// Fix (guide T3+T4): 3 x 16KB W buffers; per step:
//   issue loads(s+1) -> buf[(s+1)%3]   (readers of that buf finished before
//                                       the PREVIOUS barrier -> overwrite safe)
//   s_waitcnt vmcnt(4)                 (own loads(s) done; s+1's stay in flight)
//   s_barrier + sched_barrier(0)       (cross-wave publish, no drain)
// Last step uses vmcnt(0). wnorm loads hoisted to c==0 (16 regs) so their
// compiler waits have ~7 steps of slack and never force prefetch completion
// (vmcnt FIFO: waiting for a younger op only forces OLDER ops).
// LDS = Xl 32K + 3x16K W = 80 KB exactly -> 2 blocks/CU. Xh prologue scratch
// and xns overlay live inside the W-buffer region and die before first use.
//
// Numerics (verified rounds 2-9, unchanged): dist = fp32( fp32(xnorm+wnorm)
// - fp32(2dot) ), dot = fp16x2-split 3-product MFMA in chunk-ascending order
// (hi; ah*bl; al*bh), W pre-scaled by 1024 (exact pow2), lo terms scaled 2^24;
// xnorm f64 (oct-partials, shfl-combined); argmin strict '<' ascending k +
// index-min tie-break. W LDS region bytes identical to rounds 6-9.

#define VQ_B   32
#define VQ_D   256
#define VQ_T   2048
#define VQ_K   1024

typedef _Float16 f16x8 __attribute__((ext_vector_type(8)));
typedef _Float16 f16x4 __attribute__((ext_vector_type(4)));
typedef float    f32x4 __attribute__((ext_vector_type(4)));

#define GLOAD_LDS16(gaddr, laddr) \
  __builtin_amdgcn_global_load_lds((const __attribute__((address_space(1))) void*)(gaddr), \
                                   (__attribute__((address_space(3))) void*)(laddr), 16, 0, 0)

// ---------------- kernel 1: W prep only (64 blocks), verified round-5 body.
__global__ __launch_bounds__(256) void vq_wprep_kernel(
    const float* __restrict__ w, float* __restrict__ wnorm,
    _Float16* __restrict__ Wh, _Float16* __restrict__ Wl)
{
    __shared__ double ws_[16][16];
    const int tid = threadIdx.x;
    const int kk  = tid >> 4;
    const int dg  = tid & 15;
    const int k   = blockIdx.x * 16 + kk;
    const float* src = w + (size_t)k * VQ_D + dg * 16;
    double s = 0.0;
    #pragma unroll
    for (int q = 0; q < 4; ++q) {
        float4 v = *(const float4*)(src + q * 4);
        s += (double)v.x * v.x + (double)v.y * v.y
           + (double)v.z * v.z + (double)v.w * v.w;
        const float e4[4] = {v.x, v.y, v.z, v.w};
        f16x4 hv, lv;
        #pragma unroll
        for (int j = 0; j < 4; ++j) {
            const float es = e4[j] * 1024.0f;          // exact pow2 scale
            const _Float16 h = (_Float16)es;
            hv[j] = h;
            lv[j] = (_Float16)((es - (float)h) * 16777216.0f);
        }
        *(f16x4*)(Wh + (size_t)k * VQ_D + dg * 16 + q * 4) = hv;
        *(f16x4*)(Wl + (size_t)k * VQ_D + dg * 16 + q * 4) = lv;
    }
    ws_[kk][dg] = s;
    __syncthreads();
    if (dg == 0) {
        double acc = 0.0;
        #pragma unroll
        for (int g = 0; g < 16; ++g) acc += ws_[kk][g];  // fixed order
        wnorm[k] = (float)acc;
    }
}

// ---------------- kernel 2: reg-resident-X MFMA GEMM, counted-vmcnt pipeline
// 1024 blocks (b = blk>>5, t-tile 64), 4 waves: wm = k-half, wn = t-half.
// Wave tile = 64 k x 32 t (frags 4x2).
// LDS: [0,32K)  Xl persistent (layout ((c*4+oct)*64 + t)*16B)
//      [32K,80K) W ring buffer: 3 x 16 regions x 1024 B
//                (regions 0-7 Wh, 8-15 Wl; region byte m16*16+quad*256).
//      prologue overlays: Xh scratch at [32K,64K), xns at [64K,64K+256).
__global__ __launch_bounds__(256, 2) void vq_mfma_kernel(
    const _Float16* __restrict__ Wh, const _Float16* __restrict__ Wl,
    const float* __restrict__ inp,
    const float* __restrict__ wnorm,
    const float* __restrict__ w,
    float* __restrict__ outq, float* __restrict__ outi)
{
    __shared__ alignas(16) char lds[81920];
    char* Xl  = lds;
    char* WB  = lds + 32768;                  // 3 x 16KB ring
    char* Xhs = lds + 32768;                  // prologue scratch (buf0+buf1)
    float* xns = (float*)(lds + 65536);       // prologue overlay (buf2)

    const int tid  = threadIdx.x;
    const int lane = tid & 63;
    const int wv   = tid >> 6;                // wave 0..3
    const int m16  = lane & 15;
    const int quad = lane >> 4;
    const int wm   = wv & 1;                  // k half (0..63 / 64..127)
    const int wn   = wv >> 1;                 // t half (0..31 / 32..63)
    const int b    = blockIdx.x >> 5;
    const int tt0  = (blockIdx.x & 31) * 64;
    const long bt  = (long)b * VQ_T + tt0;

    // ---- prologue: load raw X once, split, stage Xh (scratch) + Xl (LDS),
    // accumulate xnorm in f64 (verified order: d = c*32 + oct*8 + j ascending,
    // oct-partials combined by shfl butterfly).
    const int xt = m16 + wv * 16;
    double xacc = 0.0;
    {
        float xv[2][8];
        const float* xp0 = inp + ((size_t)b * VQ_D + quad * 8) * VQ_T + tt0 + xt;
        #pragma unroll
        for (int j = 0; j < 8; ++j)
            xv[0][j] = xp0[(size_t)j * VQ_T];
        #pragma unroll
        for (int c = 0; c < 8; ++c) {
            if (c < 7) {
                const float* xpn = inp
                    + ((size_t)b * VQ_D + (c + 1) * 32 + quad * 8) * VQ_T
                    + tt0 + xt;
                #pragma unroll
                for (int j = 0; j < 8; ++j)
                    xv[(c + 1) & 1][j] = xpn[(size_t)j * VQ_T];
            }
            f16x8 hv, lv;
            #pragma unroll
            for (int j = 0; j < 8; ++j) {
                const float x = xv[c & 1][j];
                xacc += (double)x * (double)x;             // ascending d
                const _Float16 h = (_Float16)x;
                hv[j] = h;
                lv[j] = (_Float16)((x - (float)h) * 16777216.0f);
            }
            const int off = ((c * 4 + quad) * 64 + xt) * 16;
            *(f16x8*)(Xhs + off) = hv;
            *(f16x8*)(Xl  + off) = lv;
        }
    }
    xacc += __shfl_xor(xacc, 16, 64);
    xacc += __shfl_xor(xacc, 32, 64);
    if (quad == 0) xns[xt] = (float)xacc;
    __syncthreads();                             // X staged + xns visible

    // ---- one-time: wave's B hi fragments -> registers (reused by all 8 kg)
    f16x8 bhr[8][2];
    #pragma unroll
    for (int c = 0; c < 8; ++c)
        #pragma unroll
        for (int f = 0; f < 2; ++f)
            bhr[c][f] = *(const f16x8*)(Xhs +
                ((c * 4 + quad) * 64 + wn * 32 + f * 16 + m16) * 16);
    float xnr[2];
    #pragma unroll
    for (int f = 0; f < 2; ++f)
        xnr[f] = xns[wn * 32 + f * 16 + m16];
    __syncthreads();                             // scratch + xns dead -> W ring

    // ---- W staging pointers: wave wv stages regions wv*4..wv*4+3
    // (set = wv>>1 -> Wh/Wl, hf = wv&1, f = i). Source = 64B row-chunks.
    const char* gbase = (const char*)((wv >> 1) ? Wl : Wh);
    const char* gp[4];
    #pragma unroll
    for (int i = 0; i < 4; ++i)
        gp[i] = gbase + (size_t)((wv & 1) * 64 + i * 16 + m16) * 512 + quad * 16;

    // issue W(step 0) into ring buf 0
    #pragma unroll
    for (int i = 0; i < 4; ++i)
        GLOAD_LDS16(gp[i], WB + (wv * 4 + i) * 1024);
    #pragma unroll
    for (int i = 0; i < 4; ++i) gp[i] += 64;     // advance for step-1 issue

    float bestv[2] = {3.0e38f, 3.0e38f};
    int   besti[2] = {0, 0};
    f32x4 acch[4][2], accl[4][2];
    float wnr16[16];
    int cur = 0, nxt = 1;

    // ---- main loop: 8 k-groups x 8 unrolled d-chunks, one barrier per step,
    // vmcnt never drained below the next step's 4 in-flight loads.
    for (int g = 0; g < 8; ++g) {
        #pragma unroll
        for (int c = 0; c < 8; ++c) {
            // issue loads(s+1) into buf[nxt]; its readers (step s-2) finished
            // before the PREVIOUS barrier -> overwrite safe.
            if (g < 7 || c < 7) {
                #pragma unroll
                for (int i = 0; i < 4; ++i)
                    GLOAD_LDS16(gp[i], WB + nxt * 16384 + (wv * 4 + i) * 1024);
                const long adv = (c == 6) ? (65536L - 448L) : 64L;
                #pragma unroll
                for (int i = 0; i < 4; ++i) gp[i] += adv;
                asm volatile("s_waitcnt vmcnt(4)" ::: "memory");
            } else {
                asm volatile("s_waitcnt vmcnt(0)" ::: "memory");
            }
            __builtin_amdgcn_s_barrier();        // all waves' loads(s) done
            __builtin_amdgcn_sched_barrier(0);   // no hoisting above barrier

            char* const Wcur = WB + cur * 16384;

            if (c == 0) {
                #pragma unroll
                for (int fm = 0; fm < 4; ++fm)
                    #pragma unroll
                    for (int fn = 0; fn < 2; ++fn) {
                        acch[fm][fn] = (f32x4){0.f, 0.f, 0.f, 0.f};
                        accl[fm][fn] = (f32x4){0.f, 0.f, 0.f, 0.f};
                    }
                // hoisted wnorm loads: 7 steps of slack before use at c==7;
                // younger than this step's prefetch -> their waits never
                // force later prefetches to complete.
                #pragma unroll
                for (int fm = 0; fm < 4; ++fm)
                    #pragma unroll
                    for (int r = 0; r < 4; ++r)
                        wnr16[fm * 4 + r] =
                            wnorm[g * 128 + wm * 64 + fm * 16 + quad * 4 + r];
            }

            f16x8 ah[4], al[4], bl[2];
            #pragma unroll
            for (int fm = 0; fm < 4; ++fm) {
                ah[fm] = *(const f16x8*)(Wcur + (wm * 4 + fm) * 1024 + lane * 16);
                al[fm] = *(const f16x8*)(Wcur + (8 + wm * 4 + fm) * 1024 + lane * 16);
            }
            #pragma unroll
            for (int f = 0; f < 2; ++f)
                bl[f] = *(const f16x8*)(Xl +
                    ((c * 4 + quad) * 64 + wn * 32 + f * 16 + m16) * 16);

            #pragma unroll
            for (int fm = 0; fm < 4; ++fm)
                #pragma unroll
                for (int fn = 0; fn < 2; ++fn) {
                    acch[fm][fn] = __builtin_amdgcn_mfma_f32_16x16x32_f16(
                        ah[fm], bhr[c][fn], acch[fm][fn], 0, 0, 0);
                    accl[fm][fn] = __builtin_amdgcn_mfma_f32_16x16x32_f16(
                        ah[fm], bl[fn], accl[fm][fn], 0, 0, 0);
                    accl[fm][fn] = __builtin_amdgcn_mfma_f32_16x16x32_f16(
                        al[fm], bhr[c][fn], accl[fm][fn], 0, 0, 0);
                }

            if (c == 7) {
                const int k0 = g * 128;
                // scores, reference fp32 rounding chain; strict '<' over
                // ascending k => ties resolve to lowest index (np.argmin)
                #pragma unroll
                for (int fm = 0; fm < 4; ++fm) {
                    #pragma unroll
                    for (int r = 0; r < 4; ++r) {
                        const int kg = k0 + wm * 64 + fm * 16 + quad * 4 + r;
                        const float wnk = wnr16[fm * 4 + r];
                        #pragma unroll
                        for (int fn = 0; fn < 2; ++fn) {
                            const float t1 = xnr[fn] + wnk;
                            const float d2 = (acch[fm][fn][r]
                                              + accl[fm][fn][r] * 5.9604644775390625e-8f)
                                             * 0.001953125f;
                            const float sc = t1 - d2;
                            if (sc < bestv[fn]) { bestv[fn] = sc; besti[fn] = kg; }
                        }
                    }
                }
            }
            cur = nxt;
            nxt = (nxt == 2) ? 0 : nxt + 1;
        }
    }

    // cross-lane argmin: lanes {c, c+16, c+32, c+48} share a t-column
    float rv[2]; int ri[2];
    #pragma unroll
    for (int fn = 0; fn < 2; ++fn) {
        float bv = bestv[fn]; int bi = besti[fn];
        #pragma unroll
        for (int mask = 16; mask <= 32; mask <<= 1) {
            const float ov = __shfl_xor(bv, mask, 64);
            const int   oi = __shfl_xor(bi, mask, 64);
            if (ov < bv || (ov == bv && oi < bi)) { bv = ov; bi = oi; }
        }
        rv[fn] = bv; ri[fn] = bi;
    }

    // cross-wave (wm 0 vs 1) reduce via LDS overlay
    __syncthreads();
    float* sv = (float*)lds;                 // [2][64]
    int*   si = (int*)(lds + 1024);          // [2][64]
    if (quad == 0) {
        #pragma unroll
        for (int fn = 0; fn < 2; ++fn) {
            const int tl = wn * 32 + fn * 16 + m16;
            sv[wm * 64 + tl] = rv[fn];
            si[wm * 64 + tl] = ri[fn];
        }
    }
    __syncthreads();
    if (tid < 64) {
        const float v0 = sv[tid], v1 = sv[64 + tid];
        const int   i0 = si[tid], i1 = si[64 + tid];
        const int   bi = (v1 < v0 || (v1 == v0 && i1 < i0)) ? i1 : i0;
        si[tid] = bi;
        outi[bt + tid] = (float)bi;
    }
    __syncthreads();

    // quantized output: outq[b][d][t] = w[best[t]][d]  (verified epilogue)
    {
        const int t  = tid & 63;
        const int dq = tid >> 6;
        const int bi = si[t];
        const float* wrow = w + (size_t)bi * VQ_D + dq * 64;
        float* obase = outq + ((size_t)b * VQ_D + (size_t)dq * 64) * VQ_T + tt0 + t;
        #pragma unroll 4
        for (int dd = 0; dd < 64; dd += 4) {
            float4 v = *(const float4*)(wrow + dd);
            obase[(size_t)(dd + 0) * VQ_T] = v.x;
            obase[(size_t)(dd + 1) * VQ_T] = v.y;
            obase[(size_t)(dd + 2) * VQ_T] = v.z;
            obase[(size_t)(dd + 3) * VQ_T] = v.w;
        }
    }
}

extern "C" void kernel_launch(void* const* d_in, const int* in_sizes, int n_in,
                              void* d_out, int out_size, void* d_ws, size_t ws_size,
                              hipStream_t stream) {
    const float* inp = (const float*)d_in[0];
    const float* w   = (const float*)d_in[1];
    float* outq  = (float*)d_out;
    float* outi  = outq + (size_t)VQ_B * VQ_D * VQ_T;   // indices appended flat

    float*    wnorm = (float*)d_ws;                     // [1024]
    _Float16* Wh    = (_Float16*)(wnorm + VQ_K);        // [1024*256]
    _Float16* Wl    = Wh + (size_t)VQ_K * VQ_D;
    // total ws use: ~1.03 MB

    vq_wprep_kernel<<<dim3(VQ_K / 16), dim3(256), 0, stream>>>(w, wnorm, Wh, Wl);
    vq_mfma_kernel<<<dim3(VQ_B * (VQ_T / 64)), dim3(256), 0, stream>>>(
        Wh, Wl, inp, wnorm, w, outq, outi);
}